// Round 6
// baseline (24.402 us; speedup 1.0000x reference)
//
#include <hip/hip_runtime.h>

#define TOT    400000            // B*N total nodes
#define FI     64                // in features
#define HD     16                // hidden dim
#define WTILE  64                // nodes per wave (4 MFMA groups of 16)
#define NWAVES (TOT / WTILE)     // 6250 — exact, zero tail
#define NBLKS  ((NWAVES + 3) / 4)

typedef _Float16 f16x8 __attribute__((ext_vector_type(8)));
typedef float    f32x4 __attribute__((ext_vector_type(4)));

// edge_index.expand(B,2,E).reshape(2,-1) makes row==col elementwise
// (flat idx = b*2E + r*E + e; +8E only shifts b by 4) -> every edge is a
// self-edge -> GCNConv == identity + bias. Network = per-node MLP:
//   out = relu(relu(x@W1+b1)@W2+b2)@Wfc + bfc
//
// Matrix pipe via SWAPPED operands (D = W^T . X^T), m89-verified layouts.
// Round 6: one wave = one 64-node tile, all 16 dwordx4 loads issued
// upfront (256 B/lane outstanding -> 4x queue depth), compute drains
// group-by-group with counted vmcnt. No loop, no grid-stride tail.
__global__ __launch_bounds__(256, 4) void k_mlp_mfma(
        const float* __restrict__ x,
        const float* __restrict__ W1, const float* __restrict__ b1,
        const float* __restrict__ W2, const float* __restrict__ b2,
        const float* __restrict__ Wfc, const float* __restrict__ bfc,
        float* __restrict__ out) {
    const int lane = threadIdx.x & 63;
    const int n    = lane & 15;      // node-in-group / D col
    const int hi   = lane >> 4;      // 0..3
    const int wid  = blockIdx.x * 4 + (threadIdx.x >> 6);
    if (wid >= NWAVES) return;

    // ---- issue ALL x loads first (16 independent dwordx4 per lane) ----
    const float* base = x + ((size_t)wid * WTILE + n) * FI;
    float4 xa[4], xb[4], xc[4], xd[4];
#pragma unroll
    for (int g = 0; g < 4; ++g) {
        const float* row = base + g * 16 * FI;
        xa[g] = *reinterpret_cast<const float4*>(row + hi * 8);
        xb[g] = *reinterpret_cast<const float4*>(row + hi * 8 + 4);
        xc[g] = *reinterpret_cast<const float4*>(row + 32 + hi * 8);
        xd[g] = *reinterpret_cast<const float4*>(row + 32 + hi * 8 + 4);
    }

    // ---- weight fragments (VGPR-resident, wave-uniform source) ----
    f16x8 a1f[2];
#pragma unroll
    for (int ks = 0; ks < 2; ++ks)
#pragma unroll
        for (int i = 0; i < 8; ++i)
            a1f[ks][i] = (_Float16)W1[(ks * 32 + hi * 8 + i) * HD + n];

    f16x8 a2f;
    if (hi < 2) {
#pragma unroll
        for (int i = 0; i < 8; ++i)
            a2f[i] = (_Float16)W2[(hi * 8 + i) * HD + n];
    } else {
#pragma unroll
        for (int i = 0; i < 8; ++i)
            a2f[i] = (_Float16)0.0f;
    }

    const float4 b1p = *reinterpret_cast<const float4*>(b1 + hi * 4);
    const float4 b2p = *reinterpret_cast<const float4*>(b2 + hi * 4);
    const float4 wfp = *reinterpret_cast<const float4*>(Wfc + hi * 4);
    const float  bf  = bfc[0];

    // bpermute source lanes for layer-2 B-fragment assembly
    const int src0 = (((hi * 2)     & 3) * 16 + n) * 4;   // i = 0..3
    const int src1 = (((hi * 2 + 1) & 3) * 16 + n) * 4;   // i = 4..7
    const bool live = (hi < 2);                           // k<16 rows only

    // ---- compute the 4 groups, draining the load queue ----
#pragma unroll
    for (int g = 0; g < 4; ++g) {
        f16x8 bA, bB;
        bA[0] = (_Float16)xa[g].x; bA[1] = (_Float16)xa[g].y;
        bA[2] = (_Float16)xa[g].z; bA[3] = (_Float16)xa[g].w;
        bA[4] = (_Float16)xb[g].x; bA[5] = (_Float16)xb[g].y;
        bA[6] = (_Float16)xb[g].z; bA[7] = (_Float16)xb[g].w;
        bB[0] = (_Float16)xc[g].x; bB[1] = (_Float16)xc[g].y;
        bB[2] = (_Float16)xc[g].z; bB[3] = (_Float16)xc[g].w;
        bB[4] = (_Float16)xd[g].x; bB[5] = (_Float16)xd[g].y;
        bB[6] = (_Float16)xd[g].z; bB[7] = (_Float16)xd[g].w;

        f32x4 acc = {0.f, 0.f, 0.f, 0.f};
        acc = __builtin_amdgcn_mfma_f32_16x16x32_f16(a1f[0], bA, acc, 0, 0, 0);
        acc = __builtin_amdgcn_mfma_f32_16x16x32_f16(a1f[1], bB, acc, 0, 0, 0);

        float t0 = fmaxf(acc[0] + b1p.x, 0.f);
        float t1 = fmaxf(acc[1] + b1p.y, 0.f);
        float t2 = fmaxf(acc[2] + b1p.z, 0.f);
        float t3 = fmaxf(acc[3] + b1p.w, 0.f);

        float g0 = __int_as_float(__builtin_amdgcn_ds_bpermute(src0, __float_as_int(t0)));
        float g1 = __int_as_float(__builtin_amdgcn_ds_bpermute(src0, __float_as_int(t1)));
        float g2 = __int_as_float(__builtin_amdgcn_ds_bpermute(src0, __float_as_int(t2)));
        float g3 = __int_as_float(__builtin_amdgcn_ds_bpermute(src0, __float_as_int(t3)));
        float g4 = __int_as_float(__builtin_amdgcn_ds_bpermute(src1, __float_as_int(t0)));
        float g5 = __int_as_float(__builtin_amdgcn_ds_bpermute(src1, __float_as_int(t1)));
        float g6 = __int_as_float(__builtin_amdgcn_ds_bpermute(src1, __float_as_int(t2)));
        float g7 = __int_as_float(__builtin_amdgcn_ds_bpermute(src1, __float_as_int(t3)));
        f16x8 b2f;
        b2f[0] = (_Float16)(live ? g0 : 0.f);
        b2f[1] = (_Float16)(live ? g1 : 0.f);
        b2f[2] = (_Float16)(live ? g2 : 0.f);
        b2f[3] = (_Float16)(live ? g3 : 0.f);
        b2f[4] = (_Float16)(live ? g4 : 0.f);
        b2f[5] = (_Float16)(live ? g5 : 0.f);
        b2f[6] = (_Float16)(live ? g6 : 0.f);
        b2f[7] = (_Float16)(live ? g7 : 0.f);

        f32x4 acc2 = {0.f, 0.f, 0.f, 0.f};
        acc2 = __builtin_amdgcn_mfma_f32_16x16x32_f16(a2f, b2f, acc2, 0, 0, 0);

        float u0 = fmaxf(acc2[0] + b2p.x, 0.f);
        float u1 = fmaxf(acc2[1] + b2p.y, 0.f);
        float u2 = fmaxf(acc2[2] + b2p.z, 0.f);
        float u3 = fmaxf(acc2[3] + b2p.w, 0.f);
        float s = u0 * wfp.x + u1 * wfp.y + u2 * wfp.z + u3 * wfp.w;
        s += __shfl_xor(s, 16, 64);
        s += __shfl_xor(s, 32, 64);
        if (hi == 0) out[wid * WTILE + g * 16 + n] = s + bf;
    }
}

extern "C" void kernel_launch(void* const* d_in, const int* in_sizes, int n_in,
                              void* d_out, int out_size, void* d_ws, size_t ws_size,
                              hipStream_t stream) {
    const float* x   = (const float*)d_in[0];
    // d_in[1] = edge_index — unused: row==col makes the conv identity+bias.
    const float* W1  = (const float*)d_in[2];
    const float* b1  = (const float*)d_in[3];
    const float* W2  = (const float*)d_in[4];
    const float* b2  = (const float*)d_in[5];
    const float* Wfc = (const float*)d_in[6];
    const float* bfc = (const float*)d_in[7];
    float* out = (float*)d_out;

    k_mlp_mfma<<<NBLKS, 256, 0, stream>>>(x, W1, b1, W2, b2, Wfc, bfc, out);
}

// Round 7
// 22.581 us; speedup vs baseline: 1.0806x; 1.0806x over previous
//
#include <hip/hip_runtime.h>

#define TOT   400000            // B*N total nodes
#define FI    64                // in features
#define HD    16                // hidden dim
#define TILES (TOT / 16)        // 25000 16-node tiles
#define NBLK  2048
#define NWAVE (NBLK * 4)        // 8192 waves, grid-stride

#define LROW  68                // floats per LDS row (272 B = 256 + 16 pad, keeps 16B align)
#define LWAVE (16 * LROW)       // 1088 floats per wave-private buffer

typedef _Float16 f16x8 __attribute__((ext_vector_type(8)));
typedef float    f32x4 __attribute__((ext_vector_type(4)));

// edge_index.expand(B,2,E).reshape(2,-1) makes row==col elementwise
// (flat idx = b*2E + r*E + e; +8E only shifts b by 4) -> every edge is a
// self-edge -> GCNConv == identity + bias. Network = per-node MLP:
//   out = relu(relu(x@W1+b1)@W2+b2)@Wfc + bfc
//
// Matrix pipe via SWAPPED operands (D = W^T . X^T), m89-verified layouts.
// Round 7: loads made lane-LINEAR (4x contiguous 1KB bursts per 4KB tile);
// the node<->lane transpose the MFMA B-fragment needs is done through a
// wave-PRIVATE padded LDS buffer (row stride 272B: write banks 4*(slot&7),
// read banks (4n+8hi)&31 -- conflict-free per octet; no barriers, in-order
// DS pipe within a wave). Tests the strided-load theory for the 4.7 vs
// ~6.3-7.0 TB/s gap.
__global__ __launch_bounds__(256, 4) void k_mlp_mfma(
        const float* __restrict__ x,
        const float* __restrict__ W1, const float* __restrict__ b1,
        const float* __restrict__ W2, const float* __restrict__ b2,
        const float* __restrict__ Wfc, const float* __restrict__ bfc,
        float* __restrict__ out) {
    __shared__ float lds[4 * LWAVE];            // 17408 B per block
    const int lane = threadIdx.x & 63;
    const int n    = lane & 15;      // node-in-tile / D col
    const int hi   = lane >> 4;      // 0..3
    const int w    = threadIdx.x >> 6;
    const int wid  = blockIdx.x * 4 + w;
    float* lb = lds + w * LWAVE;     // wave-private transpose buffer

    // ---- weight fragments (VGPR-resident, amortized over ~3 tiles) ----
    f16x8 a1f[2];
#pragma unroll
    for (int ks = 0; ks < 2; ++ks)
#pragma unroll
        for (int i = 0; i < 8; ++i)
            a1f[ks][i] = (_Float16)W1[(ks * 32 + hi * 8 + i) * HD + n];

    f16x8 a2f;
    if (hi < 2) {
#pragma unroll
        for (int i = 0; i < 8; ++i)
            a2f[i] = (_Float16)W2[(hi * 8 + i) * HD + n];
    } else {
#pragma unroll
        for (int i = 0; i < 8; ++i)
            a2f[i] = (_Float16)0.0f;
    }

    const float4 b1p = *reinterpret_cast<const float4*>(b1 + hi * 4);
    const float4 b2p = *reinterpret_cast<const float4*>(b2 + hi * 4);
    const float4 wfp = *reinterpret_cast<const float4*>(Wfc + hi * 4);
    const float  bf  = bfc[0];

    // bpermute source lanes for layer-2 B-fragment assembly
    const int src0 = (((hi * 2)     & 3) * 16 + n) * 4;   // i = 0..3
    const int src1 = (((hi * 2 + 1) & 3) * 16 + n) * 4;   // i = 4..7
    const bool live = (hi < 2);                           // k<16 rows only

    // LDS addresses (loop-invariant)
    const int wrow  = lane >> 4;          // write row sub-index 0..3
    const int wslot = (lane & 15) * 4;    // write col in floats
    float* wp0 = lb + (0 * 4 + wrow) * LROW + wslot;
    float* wp1 = lb + (1 * 4 + wrow) * LROW + wslot;
    float* wp2 = lb + (2 * 4 + wrow) * LROW + wslot;
    float* wp3 = lb + (3 * 4 + wrow) * LROW + wslot;
    const float* rpa = lb + n * LROW + hi * 8;        // k = hi*8 ..
    const float* rpc = lb + n * LROW + 32 + hi * 8;   // k = 32 + hi*8 ..

    for (int t = wid; t < TILES; t += NWAVE) {
        // ---- 4 lane-linear 1KB loads covering the 4KB tile ----
        const float* gb = x + (size_t)t * (16 * FI);
        float4 v0 = *reinterpret_cast<const float4*>(gb + lane * 4);
        float4 v1 = *reinterpret_cast<const float4*>(gb + 256 + lane * 4);
        float4 v2 = *reinterpret_cast<const float4*>(gb + 512 + lane * 4);
        float4 v3 = *reinterpret_cast<const float4*>(gb + 768 + lane * 4);

        // ---- stage to padded wave-private LDS (transpose) ----
        *reinterpret_cast<float4*>(wp0) = v0;
        *reinterpret_cast<float4*>(wp1) = v1;
        *reinterpret_cast<float4*>(wp2) = v2;
        *reinterpret_cast<float4*>(wp3) = v3;

        // ---- read back in MFMA B-fragment pattern ----
        float4 xa = *reinterpret_cast<const float4*>(rpa);
        float4 xb = *reinterpret_cast<const float4*>(rpa + 4);
        float4 xc = *reinterpret_cast<const float4*>(rpc);
        float4 xd = *reinterpret_cast<const float4*>(rpc + 4);

        f16x8 bA, bB;
        bA[0] = (_Float16)xa.x; bA[1] = (_Float16)xa.y;
        bA[2] = (_Float16)xa.z; bA[3] = (_Float16)xa.w;
        bA[4] = (_Float16)xb.x; bA[5] = (_Float16)xb.y;
        bA[6] = (_Float16)xb.z; bA[7] = (_Float16)xb.w;
        bB[0] = (_Float16)xc.x; bB[1] = (_Float16)xc.y;
        bB[2] = (_Float16)xc.z; bB[3] = (_Float16)xc.w;
        bB[4] = (_Float16)xd.x; bB[5] = (_Float16)xd.y;
        bB[6] = (_Float16)xd.z; bB[7] = (_Float16)xd.w;

        f32x4 acc = {0.f, 0.f, 0.f, 0.f};
        acc = __builtin_amdgcn_mfma_f32_16x16x32_f16(a1f[0], bA, acc, 0, 0, 0);
        acc = __builtin_amdgcn_mfma_f32_16x16x32_f16(a1f[1], bB, acc, 0, 0, 0);

        float t0 = fmaxf(acc[0] + b1p.x, 0.f);
        float t1 = fmaxf(acc[1] + b1p.y, 0.f);
        float t2 = fmaxf(acc[2] + b1p.z, 0.f);
        float t3 = fmaxf(acc[3] + b1p.w, 0.f);

        float g0 = __int_as_float(__builtin_amdgcn_ds_bpermute(src0, __float_as_int(t0)));
        float g1 = __int_as_float(__builtin_amdgcn_ds_bpermute(src0, __float_as_int(t1)));
        float g2 = __int_as_float(__builtin_amdgcn_ds_bpermute(src0, __float_as_int(t2)));
        float g3 = __int_as_float(__builtin_amdgcn_ds_bpermute(src0, __float_as_int(t3)));
        float g4 = __int_as_float(__builtin_amdgcn_ds_bpermute(src1, __float_as_int(t0)));
        float g5 = __int_as_float(__builtin_amdgcn_ds_bpermute(src1, __float_as_int(t1)));
        float g6 = __int_as_float(__builtin_amdgcn_ds_bpermute(src1, __float_as_int(t2)));
        float g7 = __int_as_float(__builtin_amdgcn_ds_bpermute(src1, __float_as_int(t3)));
        f16x8 b2f;
        b2f[0] = (_Float16)(live ? g0 : 0.f);
        b2f[1] = (_Float16)(live ? g1 : 0.f);
        b2f[2] = (_Float16)(live ? g2 : 0.f);
        b2f[3] = (_Float16)(live ? g3 : 0.f);
        b2f[4] = (_Float16)(live ? g4 : 0.f);
        b2f[5] = (_Float16)(live ? g5 : 0.f);
        b2f[6] = (_Float16)(live ? g6 : 0.f);
        b2f[7] = (_Float16)(live ? g7 : 0.f);

        f32x4 acc2 = {0.f, 0.f, 0.f, 0.f};
        acc2 = __builtin_amdgcn_mfma_f32_16x16x32_f16(a2f, b2f, acc2, 0, 0, 0);

        float u0 = fmaxf(acc2[0] + b2p.x, 0.f);
        float u1 = fmaxf(acc2[1] + b2p.y, 0.f);
        float u2 = fmaxf(acc2[2] + b2p.z, 0.f);
        float u3 = fmaxf(acc2[3] + b2p.w, 0.f);
        float s = u0 * wfp.x + u1 * wfp.y + u2 * wfp.z + u3 * wfp.w;
        s += __shfl_xor(s, 16, 64);
        s += __shfl_xor(s, 32, 64);
        if (hi == 0) out[t * 16 + n] = s + bf;
    }
}

extern "C" void kernel_launch(void* const* d_in, const int* in_sizes, int n_in,
                              void* d_out, int out_size, void* d_ws, size_t ws_size,
                              hipStream_t stream) {
    const float* x   = (const float*)d_in[0];
    // d_in[1] = edge_index — unused: row==col makes the conv identity+bias.
    const float* W1  = (const float*)d_in[2];
    const float* b1  = (const float*)d_in[3];
    const float* W2  = (const float*)d_in[4];
    const float* b2  = (const float*)d_in[5];
    const float* Wfc = (const float*)d_in[6];
    const float* bfc = (const float*)d_in[7];
    float* out = (float*)d_out;

    k_mlp_mfma<<<NBLK, 256, 0, stream>>>(x, W1, b1, W2, b2, Wfc, bfc, out);
}